// Round 5
// baseline (435.824 us; speedup 1.0000x reference)
//
#include <hip/hip_runtime.h>
#include <math.h>

#define D_MODEL 1024
#define D_INNER 2048
#define DPROJ   96      // DT_RANK + 2*D_STATE
#define DT_RANK 64
#define NSTATE  16
#define SEQ     2048
#define CL      32      // chunk length for scan
#define NCH     (SEQ/CL)            // 64
#define SCAN_SEGS 4
#define SCAN_CPS  (NCH / SCAN_SEGS) // 16 chunks per segment-lane
#define LOG2E   1.44269504088896340736f

typedef unsigned short ushort_t;
typedef short v8s __attribute__((ext_vector_type(8)));
typedef float v4f __attribute__((ext_vector_type(4)));
typedef __attribute__((address_space(3))) unsigned int as3_u32;
typedef __attribute__((address_space(1))) unsigned int as1_u32;

__device__ __forceinline__ float silu_f(float x) { return x / (1.f + expf(-x)); }

__device__ __forceinline__ ushort_t f2bf(float f) {
  union { float f; unsigned u; } x; x.f = f;
  unsigned r = x.u + 0x7fffu + ((x.u >> 16) & 1u);  // RNE; inputs finite
  return (ushort_t)(r >> 16);
}
__device__ __forceinline__ float bf2f(ushort_t b) {
  union { unsigned u; float f; } x; x.u = ((unsigned)b) << 16; return x.f;
}

// async global->LDS, 16B per lane; lds dest = wave-uniform base + lane*16
__device__ __forceinline__ void gl_lds16(const ushort_t* g, ushort_t* l) {
  __builtin_amdgcn_global_load_lds((const as1_u32*)g, (as3_u32*)l, 16, 0, 0);
}

// res = a (+ b); xn = rmsnorm(res)*w -> f32 (xnf) and/or bf16 (xnb)
__global__ __launch_bounds__(256) void addrms_kernel(
    const float* __restrict__ a, const float* __restrict__ b,
    const float* __restrict__ w, float* __restrict__ res_out,
    float* __restrict__ xnf, ushort_t* __restrict__ xnb) {
  int t = blockIdx.x;
  int tid = threadIdx.x;
  float v[4];
  float ss = 0.f;
#pragma unroll
  for (int j = 0; j < 4; ++j) {
    int dcol = tid + j * 256;
    float x = a[(size_t)t * D_MODEL + dcol];
    if (b) x += b[(size_t)t * D_MODEL + dcol];
    v[j] = x;
    ss += x * x;
  }
#pragma unroll
  for (int off = 32; off > 0; off >>= 1) ss += __shfl_down(ss, off);
  __shared__ float red[4];
  __shared__ float rmsv;
  int wid = tid >> 6, lane = tid & 63;
  if (lane == 0) red[wid] = ss;
  __syncthreads();
  if (tid == 0) {
    float s = red[0] + red[1] + red[2] + red[3];
    rmsv = rsqrtf(s / (float)D_MODEL + 1e-5f);
  }
  __syncthreads();
  float r = rmsv;
#pragma unroll
  for (int j = 0; j < 4; ++j) {
    int dcol = tid + j * 256;
    if (res_out) res_out[(size_t)t * D_MODEL + dcol] = v[j];
    float xn = v[j] * r * w[dcol];
    if (xnf) xnf[(size_t)t * D_MODEL + dcol] = xn;
    if (xnb) xnb[(size_t)t * D_MODEL + dcol] = f2bf(xn);
  }
}

__global__ __launch_bounds__(256) void f2bf_kernel(
    const float* __restrict__ in, ushort_t* __restrict__ out, int n4) {
  int i = blockIdx.x * 256 + threadIdx.x;
  if (i >= n4) return;
  float4 v = ((const float4*)in)[i];
  ushort4 o;
  o.x = f2bf(v.x); o.y = f2bf(v.y); o.z = f2bf(v.z); o.w = f2bf(v.w);
  ((ushort4*)out)[i] = o;
}

// ------------- bf16 MFMA GEMM (NT): C[m,n] = sum_k A[m,k]*B[n,k] -------------
// m97 structure: 128x128 tile, BK=32, linear LDS [128][32] bf16, global_load_lds
// width16 staging, 4 waves (2x2), 4x4 frags of 16x16x32 each.
// SPLITK>1: blockIdx.z takes K-chunk, C offset z*M*ldc (deterministic partials).
// EPI: 0 = f32 out, 1 = softplus(acc+bias[col]) -> bf16 out, 2 = bf16 out.
template <int SPLITK, bool CLAMPN, int EPI>
__global__ __launch_bounds__(256) void gemm_bt(
    const ushort_t* __restrict__ A, const ushort_t* __restrict__ B,
    void* __restrict__ Cv, const float* __restrict__ bias,
    int M, int N, int K, int lda, int ldb, int ldc) {
  __shared__ ushort_t As[128 * 32];
  __shared__ ushort_t Bs[128 * 32];
  int tid = threadIdx.x;
  int bm = blockIdx.y * 128;
  int bn = blockIdx.x * 128;
  int kchunk = K / SPLITK;
  int k0 = blockIdx.z * kchunk;

  int lane = tid & 63, wid = tid >> 6;
  int wr = wid >> 1, wc = wid & 1;
  int lr = lane & 15;
  int ko = (lane >> 4) * 8;

  int rs0 = wid * 16 + (lane >> 2);
  int segc = (lane & 3) * 8;

  v4f acc[4][4] = {};

  for (int kt = k0; kt < k0 + kchunk; kt += 32) {
#pragma unroll
    for (int s = 0; s < 2; ++s) {
      int r = s * 64 + rs0;
      int cc = kt + segc;
      gl_lds16(A + (size_t)(bm + r) * lda + cc, &As[s * 2048 + wid * 512]);
      int bc = bn + r;
      if (CLAMPN) bc = min(bc, N - 1);   // stay in-bounds; junk cols never stored
      gl_lds16(B + (size_t)bc * ldb + cc, &Bs[s * 2048 + wid * 512]);
    }
    __syncthreads();
    v8s a[4], b[4];
#pragma unroll
    for (int m = 0; m < 4; ++m)
      a[m] = *(const v8s*)&As[(wr * 64 + m * 16 + lr) * 32 + ko];
#pragma unroll
    for (int n = 0; n < 4; ++n)
      b[n] = *(const v8s*)&Bs[(wc * 64 + n * 16 + lr) * 32 + ko];
#pragma unroll
    for (int m = 0; m < 4; ++m)
#pragma unroll
      for (int n = 0; n < 4; ++n)
        acc[m][n] = __builtin_amdgcn_mfma_f32_16x16x32_bf16(a[m], b[n], acc[m][n], 0, 0, 0);
    __syncthreads();
  }

  float* Cf = (float*)Cv;
  ushort_t* Cb = (ushort_t*)Cv;
  if (SPLITK > 1) Cf += (size_t)blockIdx.z * (size_t)M * (size_t)ldc;

#pragma unroll
  for (int m = 0; m < 4; ++m) {
#pragma unroll
    for (int n = 0; n < 4; ++n) {
      int gc = bn + wc * 64 + n * 16 + lr;
      if (gc >= N) continue;
      int gr0 = bm + wr * 64 + m * 16 + (lane >> 4) * 4;
      float bv = (EPI == 1) ? bias[gc] : 0.f;
#pragma unroll
      for (int j = 0; j < 4; ++j) {
        float val = acc[m][n][j];
        if (EPI == 0) {
          Cf[(size_t)(gr0 + j) * ldc + gc] = val;
        } else if (EPI == 1) {
          float x = val + bv;
          x = fmaxf(x, 0.f) + log1pf(expf(-fabsf(x)));
          Cb[(size_t)(gr0 + j) * ldc + gc] = f2bf(x);
        } else {
          Cb[(size_t)(gr0 + j) * ldc + gc] = f2bf(val);
        }
      }
    }
  }
}

// out[idx] = sum_p part[idx + p*sz]; optional bf16 mirror
__global__ __launch_bounds__(256) void reduceN_kernel(
    const float* __restrict__ part, float* __restrict__ out,
    ushort_t* __restrict__ outb, int sz, int nparts) {
  int idx = blockIdx.x * 256 + threadIdx.x;
  if (idx >= sz) return;
  float s = 0.f;
  for (int p = 0; p < nparts; ++p) s += part[idx + (size_t)p * sz];
  out[idx] = s;
  if (outb) outb[idx] = f2bf(s);
}

// depthwise causal conv (k=4) + silu, bf16 in (xz) -> bf16 out; 4 channels/thread
__global__ __launch_bounds__(256) void conv_silu_kernel(
    const ushort_t* __restrict__ xzb, const float* __restrict__ cw,
    const float* __restrict__ cb, ushort_t* __restrict__ xcb) {
  int idx = blockIdx.x * 256 + threadIdx.x;   // over SEQ * (D_INNER/4)
  int t = idx >> 9;
  int c = (idx & 511) * 4;
  float acc[4];
  float4 cbv = *(const float4*)&cb[c];
  acc[0] = cbv.x; acc[1] = cbv.y; acc[2] = cbv.z; acc[3] = cbv.w;
  float4 wv[4];
#pragma unroll
  for (int i = 0; i < 4; ++i) wv[i] = *(const float4*)&cw[(c + i) * 4];
#pragma unroll
  for (int k = 0; k < 4; ++k) {
    int ts = t - 3 + k;
    if (ts < 0) continue;
    ushort4 x = *(const ushort4*)&xzb[(size_t)ts * 4096 + c];
    acc[0] = fmaf(bf2f(x.x), wv[0].x * 0.f + ((const float*)&wv[0])[k], acc[0]);
    acc[1] = fmaf(bf2f(x.y), ((const float*)&wv[1])[k], acc[1]);
    acc[2] = fmaf(bf2f(x.z), ((const float*)&wv[2])[k], acc[2]);
    acc[3] = fmaf(bf2f(x.w), ((const float*)&wv[3])[k], acc[3]);
  }
  // fix acc[0]: remove the bogus wv[0].x*0 term structure (it contributed 0)
  ushort4 o;
  o.x = f2bf(silu_f(acc[0]));
  o.y = f2bf(silu_f(acc[1]));
  o.z = f2bf(silu_f(acc[2]));
  o.w = f2bf(silu_f(acc[3]));
  *(ushort4*)&xcb[(size_t)t * D_INNER + c] = o;
}

// Pass A: per-chunk cumulative dA product + local end state (h0 = 0)
__global__ __launch_bounds__(256) void scan_passA_kernel(
    const ushort_t* __restrict__ dtbb, const ushort_t* __restrict__ xcb,
    const float* __restrict__ dbc, const float* __restrict__ A_log,
    float* __restrict__ aprod, float* __restrict__ hend) {
  int c = blockIdx.x;
  int d = blockIdx.y * 256 + threadIdx.x;
  float Av[NSTATE], h[NSTATE], ap[NSTATE];
#pragma unroll
  for (int n = 0; n < NSTATE; ++n) {
    Av[n] = -expf(A_log[(size_t)d * NSTATE + n]) * LOG2E;
    h[n] = 0.f;
    ap[n] = 1.f;
  }
  int t0 = c * CL;
#pragma unroll 4
  for (int tt = 0; tt < CL; ++tt) {
    int t = t0 + tt;
    float dtv = bf2f(dtbb[(size_t)t * D_INNER + d]);
    float uv  = bf2f(xcb[(size_t)t * D_INNER + d]);
    float du = dtv * uv;
    const float* Brow = &dbc[(size_t)t * DPROJ + DT_RANK];
#pragma unroll
    for (int n = 0; n < NSTATE; ++n) {
      float dA = exp2f(dtv * Av[n]);
      h[n] = fmaf(dA, h[n], du * Brow[n]);
      ap[n] *= dA;
    }
  }
  size_t base = ((size_t)c * D_INNER + d) * NSTATE;
#pragma unroll
  for (int n = 0; n < NSTATE; ++n) {
    aprod[base + n] = ap[n];
    hend[base + n] = h[n];
  }
}

// Pass B: carry across 64 chunks. Each chain (d,n) owned by 4 lanes x 16 chunks,
// (a,e) held in registers; shfl composes segment (P,E); in-register rescan
// rewrites hend with the INCOMING state per chunk.
__global__ __launch_bounds__(256) void scan_passB_kernel(
    const float* __restrict__ aprod, float* __restrict__ hend_hin) {
  int tid = threadIdx.x;
  int lane = tid & 63;
  int wave = tid >> 6;
  int seg = lane >> 4;                       // 0..3
  int chain = blockIdx.x * 64 + wave * 16 + (lane & 15);
  const size_t stride = (size_t)D_INNER * NSTATE;
  float a[SCAN_CPS], e[SCAN_CPS];
  float P = 1.f, E = 0.f;
  int c0 = seg * SCAN_CPS;
#pragma unroll
  for (int j = 0; j < SCAN_CPS; ++j) {
    a[j] = aprod[(size_t)(c0 + j) * stride + chain];
    e[j] = hend_hin[(size_t)(c0 + j) * stride + chain];
    E = fmaf(a[j], E, e[j]);
    P *= a[j];
  }
  // inclusive scan over the 4 segments (lane stride 16)
#pragma unroll
  for (int dstep = 1; dstep < SCAN_SEGS; dstep <<= 1) {
    float Pp = __shfl_up(P, dstep * 16);
    float Ep = __shfl_up(E, dstep * 16);
    if (seg >= dstep) { E = fmaf(P, Ep, E); P *= Pp; }
  }
  // exclusive prefix = inclusive of seg-1
  float Ex = __shfl_up(E, 16);
  if (seg == 0) Ex = 0.f;
  float h = Ex;
#pragma unroll
  for (int j = 0; j < SCAN_CPS; ++j) {
    hend_hin[(size_t)(c0 + j) * stride + chain] = h;
    h = fmaf(a[j], h, e[j]);
  }
}

// Pass C: rescan from hin; y = (scan + u*D) * silu(z) -> bf16
__global__ __launch_bounds__(256) void scan_passC_kernel(
    const ushort_t* __restrict__ dtbb, const ushort_t* __restrict__ xcb,
    const float* __restrict__ dbc, const float* __restrict__ A_log,
    const float* __restrict__ Dp, const ushort_t* __restrict__ xzb,
    const float* __restrict__ hin, ushort_t* __restrict__ yb) {
  int c = blockIdx.x;
  int d = blockIdx.y * 256 + threadIdx.x;
  float Av[NSTATE], h[NSTATE];
  size_t base = ((size_t)c * D_INNER + d) * NSTATE;
#pragma unroll
  for (int n = 0; n < NSTATE; ++n) {
    Av[n] = -expf(A_log[(size_t)d * NSTATE + n]) * LOG2E;
    h[n] = hin[base + n];
  }
  float Dv = Dp[d];
  int t0 = c * CL;
#pragma unroll 4
  for (int tt = 0; tt < CL; ++tt) {
    int t = t0 + tt;
    float dtv = bf2f(dtbb[(size_t)t * D_INNER + d]);
    float uv  = bf2f(xcb[(size_t)t * D_INNER + d]);
    float du = dtv * uv;
    const float* Brow = &dbc[(size_t)t * DPROJ + DT_RANK];
    const float* Crow = &dbc[(size_t)t * DPROJ + DT_RANK + NSTATE];
    float yv = 0.f;
#pragma unroll
    for (int n = 0; n < NSTATE; ++n) {
      float dA = exp2f(dtv * Av[n]);
      h[n] = fmaf(dA, h[n], du * Brow[n]);
      yv = fmaf(h[n], Crow[n], yv);
    }
    float zv = bf2f(xzb[(size_t)t * 4096 + D_INNER + d]);
    yb[(size_t)t * D_INNER + d] = f2bf((yv + uv * Dv) * silu_f(zv));
  }
}

extern "C" void kernel_launch(void* const* d_in, const int* in_sizes, int n_in,
                              void* d_out, int out_size, void* d_ws, size_t ws_size,
                              hipStream_t stream) {
  const float* h_in   = (const float*)d_in[0];
  const float* norm_w = (const float*)d_in[1];
  const float* in_w   = (const float*)d_in[2];
  const float* conv_w = (const float*)d_in[3];
  const float* conv_b = (const float*)d_in[4];
  const float* xp_w   = (const float*)d_in[5];
  const float* dt_w   = (const float*)d_in[6];
  const float* dt_b   = (const float*)d_in[7];
  const float* A_log  = (const float*)d_in[8];
  const float* Dp     = (const float*)d_in[9];
  const float* out_w  = (const float*)d_in[10];
  const float* normf  = (const float*)d_in[11];
  float* out = (float*)d_out;

  float* ws = (float*)d_ws;
  const size_t TD = (size_t)SEQ * D_MODEL;            // 2M
  const size_t TI = (size_t)SEQ * D_INNER;            // 4M
  const size_t ST = (size_t)NCH * D_INNER * NSTATE;   // 2.1M (CL=32)
  const size_t DB = (size_t)SEQ * DPROJ;              // 196608
  const size_t INW = (size_t)2 * D_INNER * D_MODEL;   // 4.19M
  const size_t XPW = (size_t)DPROJ * D_INNER;
  const size_t DTW = (size_t)D_INNER * DT_RANK;
  const size_t OUW = (size_t)D_MODEL * D_INNER;

  float* res   = ws; ws += TD;
  float* dbc   = ws; ws += DB;
  float* hbuf  = ws; ws += TD;
  float* aprod = ws; ws += ST;
  float* hend  = ws; ws += ST;   // becomes hin after passB
  float* kpart = ws; ws += 2 * TD;  // also holds 16*DB (3.1M) for x_proj
  ushort_t* hnb  = (ushort_t*)ws;
  ushort_t* xzb  = hnb + TD;        // 2*TI ushorts
  ushort_t* xcb  = xzb + 2 * TI;
  ushort_t* dtbb = xcb + TI;
  ushort_t* ybf  = dtbb + TI;
  ushort_t* dbcb = ybf + TI;
  ushort_t* inwb = dbcb + DB;
  ushort_t* xpwb = inwb + INW;
  ushort_t* dtwb = xpwb + XPW;
  ushort_t* ouwb = dtwb + DTW;

  const float* hcur = h_in;
  for (int i = 0; i < 2; ++i) {
    f2bf_kernel<<<(INW / 4 + 255) / 256, 256, 0, stream>>>(
        in_w + (size_t)i * INW, inwb, (int)(INW / 4));
    f2bf_kernel<<<(XPW / 4 + 255) / 256, 256, 0, stream>>>(
        xp_w + (size_t)i * XPW, xpwb, (int)(XPW / 4));
    f2bf_kernel<<<(DTW / 4 + 255) / 256, 256, 0, stream>>>(
        dt_w + (size_t)i * DTW, dtwb, (int)(DTW / 4));
    f2bf_kernel<<<(OUW / 4 + 255) / 256, 256, 0, stream>>>(
        out_w + (size_t)i * OUW, ouwb, (int)(OUW / 4));

    addrms_kernel<<<SEQ, 256, 0, stream>>>(hcur, i == 0 ? nullptr : res,
                                           norm_w + (size_t)i * D_MODEL, res,
                                           nullptr, hnb);
    // in_proj: [2048 x 1024] x [4096 x 1024]^T -> xzb (bf16) [2048 x 4096]
    gemm_bt<1, false, 2><<<dim3(32, 16, 1), 256, 0, stream>>>(
        hnb, inwb, xzb, nullptr, SEQ, 2 * D_INNER, D_MODEL, D_MODEL, D_MODEL, 2 * D_INNER);
    conv_silu_kernel<<<(int)(TI / 4 / 256), 256, 0, stream>>>(
        xzb, conv_w + (size_t)i * D_INNER * 4, conv_b + (size_t)i * D_INNER, xcb);
    // x_proj: [2048 x 2048] x [96 x 2048]^T, split-K=16 -> kpart (f32)
    gemm_bt<16, true, 0><<<dim3(1, 16, 16), 256, 0, stream>>>(
        xcb, xpwb, kpart, nullptr, SEQ, DPROJ, D_INNER, D_INNER, D_INNER, DPROJ);
    reduceN_kernel<<<(DB + 255) / 256, 256, 0, stream>>>(kpart, dbc, dbcb, (int)DB, 16);
    // dt_proj: [2048 x 96(use 64)] x [2048 x 64]^T -> softplus(.+b) -> dtbb (bf16)
    gemm_bt<1, false, 1><<<dim3(16, 16, 1), 256, 0, stream>>>(
        dbcb, dtwb, dtbb, dt_b + (size_t)i * D_INNER,
        SEQ, D_INNER, DT_RANK, DPROJ, DT_RANK, D_INNER);
    scan_passA_kernel<<<dim3(NCH, D_INNER / 256), 256, 0, stream>>>(
        dtbb, xcb, dbc, A_log + (size_t)i * D_INNER * NSTATE, aprod, hend);
    scan_passB_kernel<<<(D_INNER * NSTATE) / 64, 256, 0, stream>>>(aprod, hend);
    scan_passC_kernel<<<dim3(NCH, D_INNER / 256), 256, 0, stream>>>(
        dtbb, xcb, dbc, A_log + (size_t)i * D_INNER * NSTATE,
        Dp + (size_t)i * D_INNER, xzb, hend, ybf);
    // out_proj: [2048 x 2048] x [1024 x 2048]^T, split-K=2 -> kpart, reduce -> hbuf
    gemm_bt<2, false, 0><<<dim3(8, 16, 2), 256, 0, stream>>>(
        ybf, ouwb, kpart, nullptr, SEQ, D_MODEL, D_INNER, D_INNER, D_INNER, D_MODEL);
    reduceN_kernel<<<((int)TD + 255) / 256, 256, 0, stream>>>(
        kpart, hbuf, nullptr, (int)TD, 2);
    hcur = hbuf;
  }
  addrms_kernel<<<SEQ, 256, 0, stream>>>(hbuf, res, normf, nullptr, out, nullptr);
}

// Round 6
// 421.286 us; speedup vs baseline: 1.0345x; 1.0345x over previous
//
#include <hip/hip_runtime.h>
#include <math.h>

#define D_MODEL 1024
#define D_INNER 2048
#define DPROJ   96      // DT_RANK + 2*D_STATE
#define DT_RANK 64
#define NSTATE  16
#define SEQ     2048
#define CL      16      // chunk length for scan
#define NCH     (SEQ/CL)            // 128
#define SCAN_SEGS 4
#define SCAN_CPS  (NCH / SCAN_SEGS) // 32 chunks per segment-lane
#define LOG2E   1.44269504088896340736f

typedef unsigned short ushort_t;
typedef short v8s __attribute__((ext_vector_type(8)));
typedef float v4f __attribute__((ext_vector_type(4)));
typedef __attribute__((address_space(3))) unsigned int as3_u32;
typedef __attribute__((address_space(1))) unsigned int as1_u32;

__device__ __forceinline__ float silu_f(float x) { return x / (1.f + expf(-x)); }

__device__ __forceinline__ ushort_t f2bf(float f) {
  union { float f; unsigned u; } x; x.f = f;
  unsigned r = x.u + 0x7fffu + ((x.u >> 16) & 1u);  // RNE; inputs finite
  return (ushort_t)(r >> 16);
}
__device__ __forceinline__ float bf2f(ushort_t b) {
  union { unsigned u; float f; } x; x.u = ((unsigned)b) << 16; return x.f;
}

// async global->LDS, 16B per lane; lds dest = wave-uniform base + lane*16
__device__ __forceinline__ void gl_lds16(const ushort_t* g, ushort_t* l) {
  __builtin_amdgcn_global_load_lds((const as1_u32*)g, (as3_u32*)l, 16, 0, 0);
}

// res = a (+ b); xn = rmsnorm(res)*w -> f32 (xnf) and/or bf16 (xnb)
__global__ __launch_bounds__(256) void addrms_kernel(
    const float* __restrict__ a, const float* __restrict__ b,
    const float* __restrict__ w, float* __restrict__ res_out,
    float* __restrict__ xnf, ushort_t* __restrict__ xnb) {
  int t = blockIdx.x;
  int tid = threadIdx.x;
  float v[4];
  float ss = 0.f;
#pragma unroll
  for (int j = 0; j < 4; ++j) {
    int dcol = tid + j * 256;
    float x = a[(size_t)t * D_MODEL + dcol];
    if (b) x += b[(size_t)t * D_MODEL + dcol];
    v[j] = x;
    ss += x * x;
  }
#pragma unroll
  for (int off = 32; off > 0; off >>= 1) ss += __shfl_down(ss, off);
  __shared__ float red[4];
  __shared__ float rmsv;
  int wid = tid >> 6, lane = tid & 63;
  if (lane == 0) red[wid] = ss;
  __syncthreads();
  if (tid == 0) {
    float s = red[0] + red[1] + red[2] + red[3];
    rmsv = rsqrtf(s / (float)D_MODEL + 1e-5f);
  }
  __syncthreads();
  float r = rmsv;
#pragma unroll
  for (int j = 0; j < 4; ++j) {
    int dcol = tid + j * 256;
    if (res_out) res_out[(size_t)t * D_MODEL + dcol] = v[j];
    float xn = v[j] * r * w[dcol];
    if (xnf) xnf[(size_t)t * D_MODEL + dcol] = xn;
    if (xnb) xnb[(size_t)t * D_MODEL + dcol] = f2bf(xn);
  }
}

__global__ __launch_bounds__(256) void f2bf_kernel(
    const float* __restrict__ in, ushort_t* __restrict__ out, int n4) {
  int i = blockIdx.x * 256 + threadIdx.x;
  if (i >= n4) return;
  float4 v = ((const float4*)in)[i];
  ushort4 o;
  o.x = f2bf(v.x); o.y = f2bf(v.y); o.z = f2bf(v.z); o.w = f2bf(v.w);
  ((ushort4*)out)[i] = o;
}

// ------------- bf16 MFMA GEMM (NT): C[m,n] = sum_k A[m,k]*B[n,k] -------------
// m97 structure: 128x128 tile, BK=32, linear LDS [128][32] bf16, global_load_lds
// width16 staging, 4 waves (2x2), 4x4 frags of 16x16x32 each.
// SPLITK>1: blockIdx.z takes K-chunk, C offset z*M*ldc (deterministic partials).
// EPI: 0 = f32 out, 1 = softplus(acc+bias[col]) -> bf16 out, 2 = bf16 out.
template <int SPLITK, bool CLAMPN, int EPI>
__global__ __launch_bounds__(256) void gemm_bt(
    const ushort_t* __restrict__ A, const ushort_t* __restrict__ B,
    void* __restrict__ Cv, const float* __restrict__ bias,
    int M, int N, int K, int lda, int ldb, int ldc) {
  __shared__ ushort_t As[128 * 32];
  __shared__ ushort_t Bs[128 * 32];
  int tid = threadIdx.x;
  int bm = blockIdx.y * 128;
  int bn = blockIdx.x * 128;
  int kchunk = K / SPLITK;
  int k0 = blockIdx.z * kchunk;

  int lane = tid & 63, wid = tid >> 6;
  int wr = wid >> 1, wc = wid & 1;
  int lr = lane & 15;
  int ko = (lane >> 4) * 8;

  int rs0 = wid * 16 + (lane >> 2);
  int segc = (lane & 3) * 8;

  v4f acc[4][4] = {};

  for (int kt = k0; kt < k0 + kchunk; kt += 32) {
#pragma unroll
    for (int s = 0; s < 2; ++s) {
      int r = s * 64 + rs0;
      int cc = kt + segc;
      gl_lds16(A + (size_t)(bm + r) * lda + cc, &As[s * 2048 + wid * 512]);
      int bc = bn + r;
      if (CLAMPN) bc = min(bc, N - 1);   // stay in-bounds; junk cols never stored
      gl_lds16(B + (size_t)bc * ldb + cc, &Bs[s * 2048 + wid * 512]);
    }
    __syncthreads();
    v8s a[4], b[4];
#pragma unroll
    for (int m = 0; m < 4; ++m)
      a[m] = *(const v8s*)&As[(wr * 64 + m * 16 + lr) * 32 + ko];
#pragma unroll
    for (int n = 0; n < 4; ++n)
      b[n] = *(const v8s*)&Bs[(wc * 64 + n * 16 + lr) * 32 + ko];
#pragma unroll
    for (int m = 0; m < 4; ++m)
#pragma unroll
      for (int n = 0; n < 4; ++n)
        acc[m][n] = __builtin_amdgcn_mfma_f32_16x16x32_bf16(a[m], b[n], acc[m][n], 0, 0, 0);
    __syncthreads();
  }

  float* Cf = (float*)Cv;
  ushort_t* Cb = (ushort_t*)Cv;
  if (SPLITK > 1) Cf += (size_t)blockIdx.z * (size_t)M * (size_t)ldc;

#pragma unroll
  for (int m = 0; m < 4; ++m) {
#pragma unroll
    for (int n = 0; n < 4; ++n) {
      int gc = bn + wc * 64 + n * 16 + lr;
      if (gc >= N) continue;
      int gr0 = bm + wr * 64 + m * 16 + (lane >> 4) * 4;
      float bv = (EPI == 1) ? bias[gc] : 0.f;
#pragma unroll
      for (int j = 0; j < 4; ++j) {
        float val = acc[m][n][j];
        if (EPI == 0) {
          Cf[(size_t)(gr0 + j) * ldc + gc] = val;
        } else if (EPI == 1) {
          float x = val + bv;
          x = fmaxf(x, 0.f) + log1pf(expf(-fabsf(x)));
          Cb[(size_t)(gr0 + j) * ldc + gc] = f2bf(x);
        } else {
          Cb[(size_t)(gr0 + j) * ldc + gc] = f2bf(val);
        }
      }
    }
  }
}

// out[idx] = sum_p part[idx + p*sz]; optional bf16 mirror
__global__ __launch_bounds__(256) void reduceN_kernel(
    const float* __restrict__ part, float* __restrict__ out,
    ushort_t* __restrict__ outb, int sz, int nparts) {
  int idx = blockIdx.x * 256 + threadIdx.x;
  if (idx >= sz) return;
  float s = 0.f;
  for (int p = 0; p < nparts; ++p) s += part[idx + (size_t)p * sz];
  out[idx] = s;
  if (outb) outb[idx] = f2bf(s);
}

// depthwise causal conv (k=4) + silu, bf16 in (xz) -> bf16 out; 4 channels/thread
__global__ __launch_bounds__(256) void conv_silu_kernel(
    const ushort_t* __restrict__ xzb, const float* __restrict__ cw,
    const float* __restrict__ cb, ushort_t* __restrict__ xcb) {
  int idx = blockIdx.x * 256 + threadIdx.x;   // over SEQ * (D_INNER/4)
  int t = idx >> 9;
  int c = (idx & 511) * 4;
  float acc[4];
  float4 cbv = *(const float4*)&cb[c];
  acc[0] = cbv.x; acc[1] = cbv.y; acc[2] = cbv.z; acc[3] = cbv.w;
  float4 wv[4];
#pragma unroll
  for (int i = 0; i < 4; ++i) wv[i] = *(const float4*)&cw[(c + i) * 4];
#pragma unroll
  for (int k = 0; k < 4; ++k) {
    int ts = t - 3 + k;
    if (ts < 0) continue;
    ushort4 x = *(const ushort4*)&xzb[(size_t)ts * 4096 + c];
    acc[0] = fmaf(bf2f(x.x), ((const float*)&wv[0])[k], acc[0]);
    acc[1] = fmaf(bf2f(x.y), ((const float*)&wv[1])[k], acc[1]);
    acc[2] = fmaf(bf2f(x.z), ((const float*)&wv[2])[k], acc[2]);
    acc[3] = fmaf(bf2f(x.w), ((const float*)&wv[3])[k], acc[3]);
  }
  ushort4 o;
  o.x = f2bf(silu_f(acc[0]));
  o.y = f2bf(silu_f(acc[1]));
  o.z = f2bf(silu_f(acc[2]));
  o.w = f2bf(silu_f(acc[3]));
  *(ushort4*)&xcb[(size_t)t * D_INNER + c] = o;
}

// Pass A: per-chunk cumulative dA product + local end state (h0 = 0).
// B rows for the chunk staged in LDS (uniform-address broadcast reads).
__global__ __launch_bounds__(256) void scan_passA_kernel(
    const ushort_t* __restrict__ dtbb, const ushort_t* __restrict__ xcb,
    const float* __restrict__ dbc, const float* __restrict__ A_log,
    float* __restrict__ aprod, float* __restrict__ hend) {
  __shared__ float Bsh[CL][16];
  int c = blockIdx.x;
  int d = blockIdx.y * 256 + threadIdx.x;
  int t0 = c * CL;
  {
    int j = threadIdx.x;           // CL*16/4 = 64 float4 slots
    if (j < CL * 4) {
      int r = j >> 2, col = (j & 3) * 4;
      *(float4*)&Bsh[r][col] = *(const float4*)&dbc[(size_t)(t0 + r) * DPROJ + DT_RANK + col];
    }
  }
  float Av[NSTATE], h[NSTATE], ap[NSTATE];
#pragma unroll
  for (int n = 0; n < NSTATE; ++n) {
    Av[n] = -expf(A_log[(size_t)d * NSTATE + n]) * LOG2E;
    h[n] = 0.f;
    ap[n] = 1.f;
  }
  __syncthreads();
#pragma unroll 2
  for (int tt = 0; tt < CL; ++tt) {
    int t = t0 + tt;
    float dtv = bf2f(dtbb[(size_t)t * D_INNER + d]);
    float uv  = bf2f(xcb[(size_t)t * D_INNER + d]);
    float du = dtv * uv;
#pragma unroll
    for (int n = 0; n < NSTATE; ++n) {
      float dA = exp2f(dtv * Av[n]);
      h[n] = fmaf(dA, h[n], du * Bsh[tt][n]);
      ap[n] *= dA;
    }
  }
  size_t base = ((size_t)c * D_INNER + d) * NSTATE;
#pragma unroll
  for (int n = 0; n < NSTATE; ++n) {
    aprod[base + n] = ap[n];
    hend[base + n] = h[n];
  }
}

// Pass B: carry across 128 chunks. Each chain (d,n) owned by 4 lanes x 32 chunks,
// (a,e) in registers; shfl composes segment (P,E); in-register rescan rewrites
// hend with the INCOMING state per chunk.
__global__ __launch_bounds__(256) void scan_passB_kernel(
    const float* __restrict__ aprod, float* __restrict__ hend_hin) {
  int tid = threadIdx.x;
  int lane = tid & 63;
  int wave = tid >> 6;
  int seg = lane >> 4;                       // 0..3
  int chain = blockIdx.x * 64 + wave * 16 + (lane & 15);
  const size_t stride = (size_t)D_INNER * NSTATE;
  float a[SCAN_CPS], e[SCAN_CPS];
  float P = 1.f, E = 0.f;
  int c0 = seg * SCAN_CPS;
#pragma unroll
  for (int j = 0; j < SCAN_CPS; ++j) {
    a[j] = aprod[(size_t)(c0 + j) * stride + chain];
    e[j] = hend_hin[(size_t)(c0 + j) * stride + chain];
    E = fmaf(a[j], E, e[j]);
    P *= a[j];
  }
#pragma unroll
  for (int dstep = 1; dstep < SCAN_SEGS; dstep <<= 1) {
    float Pp = __shfl_up(P, dstep * 16);
    float Ep = __shfl_up(E, dstep * 16);
    if (seg >= dstep) { E = fmaf(P, Ep, E); P *= Pp; }
  }
  float Ex = __shfl_up(E, 16);
  if (seg == 0) Ex = 0.f;
  float h = Ex;
#pragma unroll
  for (int j = 0; j < SCAN_CPS; ++j) {
    hend_hin[(size_t)(c0 + j) * stride + chain] = h;
    h = fmaf(a[j], h, e[j]);
  }
}

// Pass C: rescan from hin; y = (scan + u*D) * silu(z) -> bf16.
// B and C rows for the chunk staged in LDS.
__global__ __launch_bounds__(256) void scan_passC_kernel(
    const ushort_t* __restrict__ dtbb, const ushort_t* __restrict__ xcb,
    const float* __restrict__ dbc, const float* __restrict__ A_log,
    const float* __restrict__ Dp, const ushort_t* __restrict__ xzb,
    const float* __restrict__ hin, ushort_t* __restrict__ yb) {
  __shared__ float BCsh[CL][32];   // [tt][0..15]=B, [16..31]=C
  int c = blockIdx.x;
  int d = blockIdx.y * 256 + threadIdx.x;
  int t0 = c * CL;
  {
    int j = threadIdx.x;           // CL*32/4 = 128 float4 slots
    if (j < CL * 8) {
      int r = j >> 3, col = (j & 7) * 4;
      *(float4*)&BCsh[r][col] = *(const float4*)&dbc[(size_t)(t0 + r) * DPROJ + DT_RANK + col];
    }
  }
  float Av[NSTATE], h[NSTATE];
  size_t base = ((size_t)c * D_INNER + d) * NSTATE;
#pragma unroll
  for (int n = 0; n < NSTATE; ++n) {
    Av[n] = -expf(A_log[(size_t)d * NSTATE + n]) * LOG2E;
    h[n] = hin[base + n];
  }
  float Dv = Dp[d];
  __syncthreads();
#pragma unroll 2
  for (int tt = 0; tt < CL; ++tt) {
    int t = t0 + tt;
    float dtv = bf2f(dtbb[(size_t)t * D_INNER + d]);
    float uv  = bf2f(xcb[(size_t)t * D_INNER + d]);
    float du = dtv * uv;
    float yv = 0.f;
#pragma unroll
    for (int n = 0; n < NSTATE; ++n) {
      float dA = exp2f(dtv * Av[n]);
      h[n] = fmaf(dA, h[n], du * BCsh[tt][n]);
      yv = fmaf(h[n], BCsh[tt][16 + n], yv);
    }
    float zv = bf2f(xzb[(size_t)t * 4096 + D_INNER + d]);
    yb[(size_t)t * D_INNER + d] = f2bf((yv + uv * Dv) * silu_f(zv));
  }
}

extern "C" void kernel_launch(void* const* d_in, const int* in_sizes, int n_in,
                              void* d_out, int out_size, void* d_ws, size_t ws_size,
                              hipStream_t stream) {
  const float* h_in   = (const float*)d_in[0];
  const float* norm_w = (const float*)d_in[1];
  const float* in_w   = (const float*)d_in[2];
  const float* conv_w = (const float*)d_in[3];
  const float* conv_b = (const float*)d_in[4];
  const float* xp_w   = (const float*)d_in[5];
  const float* dt_w   = (const float*)d_in[6];
  const float* dt_b   = (const float*)d_in[7];
  const float* A_log  = (const float*)d_in[8];
  const float* Dp     = (const float*)d_in[9];
  const float* out_w  = (const float*)d_in[10];
  const float* normf  = (const float*)d_in[11];
  float* out = (float*)d_out;

  float* ws = (float*)d_ws;
  const size_t TD = (size_t)SEQ * D_MODEL;            // 2M
  const size_t TI = (size_t)SEQ * D_INNER;            // 4M
  const size_t ST = (size_t)NCH * D_INNER * NSTATE;   // 4.19M (CL=16)
  const size_t DB = (size_t)SEQ * DPROJ;              // 196608
  const size_t INW = (size_t)2 * D_INNER * D_MODEL;   // 4.19M
  const size_t XPW = (size_t)DPROJ * D_INNER;
  const size_t DTW = (size_t)D_INNER * DT_RANK;
  const size_t OUW = (size_t)D_MODEL * D_INNER;

  float* res   = ws; ws += TD;
  float* dbc   = ws; ws += DB;
  float* hbuf  = ws; ws += TD;
  float* aprod = ws; ws += ST;
  float* hend  = ws; ws += ST;   // becomes hin after passB
  float* kpart = ws; ws += 2 * TD;  // also holds 16*DB (3.1M) for x_proj
  ushort_t* hnb  = (ushort_t*)ws;
  ushort_t* xzb  = hnb + TD;        // 2*TI ushorts
  ushort_t* xcb  = xzb + 2 * TI;
  ushort_t* dtbb = xcb + TI;
  ushort_t* ybf  = dtbb + TI;
  ushort_t* dbcb = ybf + TI;
  ushort_t* inwb = dbcb + DB;
  ushort_t* xpwb = inwb + INW;
  ushort_t* dtwb = xpwb + XPW;
  ushort_t* ouwb = dtwb + DTW;

  const float* hcur = h_in;
  for (int i = 0; i < 2; ++i) {
    f2bf_kernel<<<(INW / 4 + 255) / 256, 256, 0, stream>>>(
        in_w + (size_t)i * INW, inwb, (int)(INW / 4));
    f2bf_kernel<<<(XPW / 4 + 255) / 256, 256, 0, stream>>>(
        xp_w + (size_t)i * XPW, xpwb, (int)(XPW / 4));
    f2bf_kernel<<<(DTW / 4 + 255) / 256, 256, 0, stream>>>(
        dt_w + (size_t)i * DTW, dtwb, (int)(DTW / 4));
    f2bf_kernel<<<(OUW / 4 + 255) / 256, 256, 0, stream>>>(
        out_w + (size_t)i * OUW, ouwb, (int)(OUW / 4));

    addrms_kernel<<<SEQ, 256, 0, stream>>>(hcur, i == 0 ? nullptr : res,
                                           norm_w + (size_t)i * D_MODEL, res,
                                           nullptr, hnb);
    // in_proj: [2048 x 1024] x [4096 x 1024]^T -> xzb (bf16) [2048 x 4096]
    gemm_bt<1, false, 2><<<dim3(32, 16, 1), 256, 0, stream>>>(
        hnb, inwb, xzb, nullptr, SEQ, 2 * D_INNER, D_MODEL, D_MODEL, D_MODEL, 2 * D_INNER);
    conv_silu_kernel<<<(int)(TI / 4 / 256), 256, 0, stream>>>(
        xzb, conv_w + (size_t)i * D_INNER * 4, conv_b + (size_t)i * D_INNER, xcb);
    // x_proj: [2048 x 2048] x [96 x 2048]^T, split-K=16 -> kpart (f32)
    gemm_bt<16, true, 0><<<dim3(1, 16, 16), 256, 0, stream>>>(
        xcb, xpwb, kpart, nullptr, SEQ, DPROJ, D_INNER, D_INNER, D_INNER, DPROJ);
    reduceN_kernel<<<(DB + 255) / 256, 256, 0, stream>>>(kpart, dbc, dbcb, (int)DB, 16);
    // dt_proj: [2048 x 96(use 64)] x [2048 x 64]^T -> softplus(.+b) -> dtbb (bf16)
    gemm_bt<1, false, 1><<<dim3(16, 16, 1), 256, 0, stream>>>(
        dbcb, dtwb, dtbb, dt_b + (size_t)i * D_INNER,
        SEQ, D_INNER, DT_RANK, DPROJ, DT_RANK, D_INNER);
    scan_passA_kernel<<<dim3(NCH, D_INNER / 256), 256, 0, stream>>>(
        dtbb, xcb, dbc, A_log + (size_t)i * D_INNER * NSTATE, aprod, hend);
    scan_passB_kernel<<<(D_INNER * NSTATE) / 64, 256, 0, stream>>>(aprod, hend);
    scan_passC_kernel<<<dim3(NCH, D_INNER / 256), 256, 0, stream>>>(
        dtbb, xcb, dbc, A_log + (size_t)i * D_INNER * NSTATE,
        Dp + (size_t)i * D_INNER, xzb, hend, ybf);
    // out_proj: [2048 x 2048] x [1024 x 2048]^T, split-K=2 -> kpart, reduce -> hbuf
    gemm_bt<2, false, 0><<<dim3(8, 16, 2), 256, 0, stream>>>(
        ybf, ouwb, kpart, nullptr, SEQ, D_MODEL, D_INNER, D_INNER, D_INNER, D_MODEL);
    reduceN_kernel<<<((int)TD + 255) / 256, 256, 0, stream>>>(
        kpart, hbuf, nullptr, (int)TD, 2);
    hcur = hbuf;
  }
  addrms_kernel<<<SEQ, 256, 0, stream>>>(hbuf, res, normf, nullptr, out, nullptr);
}

// Round 7
// 389.731 us; speedup vs baseline: 1.1183x; 1.0810x over previous
//
#include <hip/hip_runtime.h>
#include <math.h>

#define D_MODEL 1024
#define D_INNER 2048
#define DPROJ   96      // DT_RANK + 2*D_STATE
#define DT_RANK 64
#define NSTATE  16
#define SEQ     2048
#define CL      16      // chunk length for scan
#define NCH     (SEQ/CL)            // 128
#define SCAN_SEGS 4
#define SCAN_CPS  (NCH / SCAN_SEGS) // 32 chunks per segment-lane
#define LOG2E   1.44269504088896340736f

typedef unsigned short ushort_t;
typedef short v8s __attribute__((ext_vector_type(8)));
typedef float v4f __attribute__((ext_vector_type(4)));
typedef __attribute__((address_space(3))) unsigned int as3_u32;
typedef __attribute__((address_space(1))) unsigned int as1_u32;

__device__ __forceinline__ float silu_f(float x) { return x / (1.f + expf(-x)); }

__device__ __forceinline__ ushort_t f2bf(float f) {
  union { float f; unsigned u; } x; x.f = f;
  unsigned r = x.u + 0x7fffu + ((x.u >> 16) & 1u);  // RNE; inputs finite
  return (ushort_t)(r >> 16);
}
__device__ __forceinline__ float bf2f(ushort_t b) {
  union { unsigned u; float f; } x; x.u = ((unsigned)b) << 16; return x.f;
}

// async global->LDS, 16B per lane; lds dest = wave-uniform base + lane*16
__device__ __forceinline__ void gl_lds16(const ushort_t* g, ushort_t* l) {
  __builtin_amdgcn_global_load_lds((const as1_u32*)g, (as3_u32*)l, 16, 0, 0);
}

// res = a (+ a2) (+ b); xn = rmsnorm(res)*w -> f32 (xnf) and/or bf16 (xnb)
// (a2 lets us consume split-K=2 GEMM partials directly, no reduce pass)
__global__ __launch_bounds__(256) void addrms_kernel(
    const float* __restrict__ a, const float* __restrict__ a2,
    const float* __restrict__ b,
    const float* __restrict__ w, float* __restrict__ res_out,
    float* __restrict__ xnf, ushort_t* __restrict__ xnb) {
  int t = blockIdx.x;
  int tid = threadIdx.x;
  float v[4];
  float ss = 0.f;
#pragma unroll
  for (int j = 0; j < 4; ++j) {
    int dcol = tid + j * 256;
    float x = a[(size_t)t * D_MODEL + dcol];
    if (a2) x += a2[(size_t)t * D_MODEL + dcol];
    if (b) x += b[(size_t)t * D_MODEL + dcol];
    v[j] = x;
    ss += x * x;
  }
#pragma unroll
  for (int off = 32; off > 0; off >>= 1) ss += __shfl_down(ss, off);
  __shared__ float red[4];
  __shared__ float rmsv;
  int wid = tid >> 6, lane = tid & 63;
  if (lane == 0) red[wid] = ss;
  __syncthreads();
  if (tid == 0) {
    float s = red[0] + red[1] + red[2] + red[3];
    rmsv = rsqrtf(s / (float)D_MODEL + 1e-5f);
  }
  __syncthreads();
  float r = rmsv;
#pragma unroll
  for (int j = 0; j < 4; ++j) {
    int dcol = tid + j * 256;
    if (res_out) res_out[(size_t)t * D_MODEL + dcol] = v[j];
    float xn = v[j] * r * w[dcol];
    if (xnf) xnf[(size_t)t * D_MODEL + dcol] = xn;
    if (xnb) xnb[(size_t)t * D_MODEL + dcol] = f2bf(xn);
  }
}

// single-dispatch f32->bf16 of all 4 weight tensors (both layers each)
__global__ __launch_bounds__(256) void f2bf_all_kernel(
    const float* __restrict__ s0, ushort_t* __restrict__ d0, int n0,
    const float* __restrict__ s1, ushort_t* __restrict__ d1, int n1,
    const float* __restrict__ s2, ushort_t* __restrict__ d2, int n2,
    const float* __restrict__ s3, ushort_t* __restrict__ d3, int n3) {
  int j = blockIdx.x * 256 + threadIdx.x;
  const float* s; ushort_t* d;
  if (j < n0) { s = s0; d = d0; }
  else {
    j -= n0;
    if (j < n1) { s = s1; d = d1; }
    else {
      j -= n1;
      if (j < n2) { s = s2; d = d2; }
      else {
        j -= n2;
        if (j >= n3) return;
        s = s3; d = d3;
      }
    }
  }
  float4 v = ((const float4*)s)[j];
  ushort4 o;
  o.x = f2bf(v.x); o.y = f2bf(v.y); o.z = f2bf(v.z); o.w = f2bf(v.w);
  ((ushort4*)d)[j] = o;
}

// ------------- bf16 MFMA GEMM (NT): C[m,n] = sum_k A[m,k]*B[n,k] -------------
// m97 structure + double-buffered prefetch: 128x128 tile, BK=32, linear LDS
// [2][128][32] bf16, global_load_lds width16; issue STAGE(t+1) BEFORE the
// ds_read+MFMA of tile t; ONE __syncthreads per K-step (its vmcnt drain is
// the prefetch wait). 4 waves (2x2), 4x4 frags of 16x16x32 each.
// SPLITK>1: blockIdx.z takes K-chunk, C offset z*M*ldc (deterministic).
// EPI: 0 = f32 out, 1 = softplus(acc+bias[col]) -> bf16 out, 2 = bf16 out.
template <int SPLITK, bool CLAMPN, int EPI>
__global__ __launch_bounds__(256) void gemm_bt(
    const ushort_t* __restrict__ A, const ushort_t* __restrict__ B,
    void* __restrict__ Cv, const float* __restrict__ bias,
    int M, int N, int K, int lda, int ldb, int ldc) {
  __shared__ ushort_t As[2][128 * 32];
  __shared__ ushort_t Bs[2][128 * 32];
  int tid = threadIdx.x;
  int bm = blockIdx.y * 128;
  int bn = blockIdx.x * 128;
  int kchunk = K / SPLITK;
  int k0 = blockIdx.z * kchunk;
  int nk = kchunk / 32;

  int lane = tid & 63, wid = tid >> 6;
  int wr = wid >> 1, wc = wid & 1;
  int lr = lane & 15;
  int ko = (lane >> 4) * 8;

  int rs0 = wid * 16 + (lane >> 2);
  int segc = (lane & 3) * 8;

  auto stage = [&](int buf, int kt) {
#pragma unroll
    for (int s = 0; s < 2; ++s) {
      int r = s * 64 + rs0;
      int cc = kt + segc;
      gl_lds16(A + (size_t)(bm + r) * lda + cc, &As[buf][s * 2048 + wid * 512]);
      int bc = bn + r;
      if (CLAMPN) bc = min(bc, N - 1);   // in-bounds; junk cols never stored
      gl_lds16(B + (size_t)bc * ldb + cc, &Bs[buf][s * 2048 + wid * 512]);
    }
  };

  v4f acc[4][4] = {};

  stage(0, k0);
  __syncthreads();          // drains vmcnt -> buf0 ready
  int cur = 0;
  for (int it = 0; it < nk; ++it) {
    if (it + 1 < nk) stage(cur ^ 1, k0 + (it + 1) * 32);   // prefetch next
    v8s a[4], b[4];
#pragma unroll
    for (int m = 0; m < 4; ++m)
      a[m] = *(const v8s*)&As[cur][(wr * 64 + m * 16 + lr) * 32 + ko];
#pragma unroll
    for (int n = 0; n < 4; ++n)
      b[n] = *(const v8s*)&Bs[cur][(wc * 64 + n * 16 + lr) * 32 + ko];
#pragma unroll
    for (int m = 0; m < 4; ++m)
#pragma unroll
      for (int n = 0; n < 4; ++n)
        acc[m][n] = __builtin_amdgcn_mfma_f32_16x16x32_bf16(a[m], b[n], acc[m][n], 0, 0, 0);
    __syncthreads();        // all reads of buf[cur] done + prefetch landed
    cur ^= 1;
  }

  float* Cf = (float*)Cv;
  ushort_t* Cb = (ushort_t*)Cv;
  if (SPLITK > 1) Cf += (size_t)blockIdx.z * (size_t)M * (size_t)ldc;

#pragma unroll
  for (int m = 0; m < 4; ++m) {
#pragma unroll
    for (int n = 0; n < 4; ++n) {
      int gc = bn + wc * 64 + n * 16 + lr;
      if (gc >= N) continue;
      int gr0 = bm + wr * 64 + m * 16 + (lane >> 4) * 4;
      float bv = (EPI == 1) ? bias[gc] : 0.f;
#pragma unroll
      for (int j = 0; j < 4; ++j) {
        float val = acc[m][n][j];
        if (EPI == 0) {
          Cf[(size_t)(gr0 + j) * ldc + gc] = val;
        } else if (EPI == 1) {
          float x = val + bv;
          x = fmaxf(x, 0.f) + log1pf(expf(-fabsf(x)));
          Cb[(size_t)(gr0 + j) * ldc + gc] = f2bf(x);
        } else {
          Cb[(size_t)(gr0 + j) * ldc + gc] = f2bf(val);
        }
      }
    }
  }
}

// out[idx] = sum_p part[idx + p*sz]; optional bf16 mirror
__global__ __launch_bounds__(256) void reduceN_kernel(
    const float* __restrict__ part, float* __restrict__ out,
    ushort_t* __restrict__ outb, int sz, int nparts) {
  int idx = blockIdx.x * 256 + threadIdx.x;
  if (idx >= sz) return;
  float s = 0.f;
  for (int p = 0; p < nparts; ++p) s += part[idx + (size_t)p * sz];
  out[idx] = s;
  if (outb) outb[idx] = f2bf(s);
}

// depthwise causal conv (k=4) + silu, bf16 in (xz) -> bf16 out; 4 channels/thread
__global__ __launch_bounds__(256) void conv_silu_kernel(
    const ushort_t* __restrict__ xzb, const float* __restrict__ cw,
    const float* __restrict__ cb, ushort_t* __restrict__ xcb) {
  int idx = blockIdx.x * 256 + threadIdx.x;   // over SEQ * (D_INNER/4)
  int t = idx >> 9;
  int c = (idx & 511) * 4;
  float acc[4];
  float4 cbv = *(const float4*)&cb[c];
  acc[0] = cbv.x; acc[1] = cbv.y; acc[2] = cbv.z; acc[3] = cbv.w;
  float4 wv[4];
#pragma unroll
  for (int i = 0; i < 4; ++i) wv[i] = *(const float4*)&cw[(c + i) * 4];
#pragma unroll
  for (int k = 0; k < 4; ++k) {
    int ts = t - 3 + k;
    if (ts < 0) continue;
    ushort4 x = *(const ushort4*)&xzb[(size_t)ts * 4096 + c];
    acc[0] = fmaf(bf2f(x.x), ((const float*)&wv[0])[k], acc[0]);
    acc[1] = fmaf(bf2f(x.y), ((const float*)&wv[1])[k], acc[1]);
    acc[2] = fmaf(bf2f(x.z), ((const float*)&wv[2])[k], acc[2]);
    acc[3] = fmaf(bf2f(x.w), ((const float*)&wv[3])[k], acc[3]);
  }
  ushort4 o;
  o.x = f2bf(silu_f(acc[0]));
  o.y = f2bf(silu_f(acc[1]));
  o.z = f2bf(silu_f(acc[2]));
  o.w = f2bf(silu_f(acc[3]));
  *(ushort4*)&xcb[(size_t)t * D_INNER + c] = o;
}

// Pass A: per-chunk cumulative dA product + local end state (h0 = 0).
// B rows for the chunk staged in LDS (uniform-address broadcast reads).
__global__ __launch_bounds__(256) void scan_passA_kernel(
    const ushort_t* __restrict__ dtbb, const ushort_t* __restrict__ xcb,
    const float* __restrict__ dbc, const float* __restrict__ A_log,
    float* __restrict__ aprod, float* __restrict__ hend) {
  __shared__ float Bsh[CL][16];
  int c = blockIdx.x;
  int d = blockIdx.y * 256 + threadIdx.x;
  int t0 = c * CL;
  {
    int j = threadIdx.x;           // CL*16/4 = 64 float4 slots
    if (j < CL * 4) {
      int r = j >> 2, col = (j & 3) * 4;
      *(float4*)&Bsh[r][col] = *(const float4*)&dbc[(size_t)(t0 + r) * DPROJ + DT_RANK + col];
    }
  }
  float Av[NSTATE], h[NSTATE], ap[NSTATE];
#pragma unroll
  for (int n = 0; n < NSTATE; ++n) {
    Av[n] = -expf(A_log[(size_t)d * NSTATE + n]) * LOG2E;
    h[n] = 0.f;
    ap[n] = 1.f;
  }
  __syncthreads();
#pragma unroll 2
  for (int tt = 0; tt < CL; ++tt) {
    int t = t0 + tt;
    float dtv = bf2f(dtbb[(size_t)t * D_INNER + d]);
    float uv  = bf2f(xcb[(size_t)t * D_INNER + d]);
    float du = dtv * uv;
#pragma unroll
    for (int n = 0; n < NSTATE; ++n) {
      float dA = exp2f(dtv * Av[n]);
      h[n] = fmaf(dA, h[n], du * Bsh[tt][n]);
      ap[n] *= dA;
    }
  }
  size_t base = ((size_t)c * D_INNER + d) * NSTATE;
#pragma unroll
  for (int n = 0; n < NSTATE; ++n) {
    aprod[base + n] = ap[n];
    hend[base + n] = h[n];
  }
}

// Pass B: carry across 128 chunks. Each chain (d,n) owned by 4 lanes x 32 chunks,
// (a,e) in registers; shfl composes segment (P,E); in-register rescan rewrites
// hend with the INCOMING state per chunk.
__global__ __launch_bounds__(256) void scan_passB_kernel(
    const float* __restrict__ aprod, float* __restrict__ hend_hin) {
  int tid = threadIdx.x;
  int lane = tid & 63;
  int wave = tid >> 6;
  int seg = lane >> 4;                       // 0..3
  int chain = blockIdx.x * 64 + wave * 16 + (lane & 15);
  const size_t stride = (size_t)D_INNER * NSTATE;
  float a[SCAN_CPS], e[SCAN_CPS];
  float P = 1.f, E = 0.f;
  int c0 = seg * SCAN_CPS;
#pragma unroll
  for (int j = 0; j < SCAN_CPS; ++j) {
    a[j] = aprod[(size_t)(c0 + j) * stride + chain];
    e[j] = hend_hin[(size_t)(c0 + j) * stride + chain];
    E = fmaf(a[j], E, e[j]);
    P *= a[j];
  }
#pragma unroll
  for (int dstep = 1; dstep < SCAN_SEGS; dstep <<= 1) {
    float Pp = __shfl_up(P, dstep * 16);
    float Ep = __shfl_up(E, dstep * 16);
    if (seg >= dstep) { E = fmaf(P, Ep, E); P *= Pp; }
  }
  float Ex = __shfl_up(E, 16);
  if (seg == 0) Ex = 0.f;
  float h = Ex;
#pragma unroll
  for (int j = 0; j < SCAN_CPS; ++j) {
    hend_hin[(size_t)(c0 + j) * stride + chain] = h;
    h = fmaf(a[j], h, e[j]);
  }
}

// Pass C: rescan from hin; y = (scan + u*D) * silu(z) -> bf16.
// B and C rows for the chunk staged in LDS.
__global__ __launch_bounds__(256) void scan_passC_kernel(
    const ushort_t* __restrict__ dtbb, const ushort_t* __restrict__ xcb,
    const float* __restrict__ dbc, const float* __restrict__ A_log,
    const float* __restrict__ Dp, const ushort_t* __restrict__ xzb,
    const float* __restrict__ hin, ushort_t* __restrict__ yb) {
  __shared__ float BCsh[CL][32];   // [tt][0..15]=B, [16..31]=C
  int c = blockIdx.x;
  int d = blockIdx.y * 256 + threadIdx.x;
  int t0 = c * CL;
  {
    int j = threadIdx.x;           // CL*32/4 = 128 float4 slots
    if (j < CL * 8) {
      int r = j >> 3, col = (j & 7) * 4;
      *(float4*)&BCsh[r][col] = *(const float4*)&dbc[(size_t)(t0 + r) * DPROJ + DT_RANK + col];
    }
  }
  float Av[NSTATE], h[NSTATE];
  size_t base = ((size_t)c * D_INNER + d) * NSTATE;
#pragma unroll
  for (int n = 0; n < NSTATE; ++n) {
    Av[n] = -expf(A_log[(size_t)d * NSTATE + n]) * LOG2E;
    h[n] = hin[base + n];
  }
  float Dv = Dp[d];
  __syncthreads();
#pragma unroll 2
  for (int tt = 0; tt < CL; ++tt) {
    int t = t0 + tt;
    float dtv = bf2f(dtbb[(size_t)t * D_INNER + d]);
    float uv  = bf2f(xcb[(size_t)t * D_INNER + d]);
    float du = dtv * uv;
    float yv = 0.f;
#pragma unroll
    for (int n = 0; n < NSTATE; ++n) {
      float dA = exp2f(dtv * Av[n]);
      h[n] = fmaf(dA, h[n], du * BCsh[tt][n]);
      yv = fmaf(h[n], BCsh[tt][16 + n], yv);
    }
    float zv = bf2f(xzb[(size_t)t * 4096 + D_INNER + d]);
    yb[(size_t)t * D_INNER + d] = f2bf((yv + uv * Dv) * silu_f(zv));
  }
}

extern "C" void kernel_launch(void* const* d_in, const int* in_sizes, int n_in,
                              void* d_out, int out_size, void* d_ws, size_t ws_size,
                              hipStream_t stream) {
  const float* h_in   = (const float*)d_in[0];
  const float* norm_w = (const float*)d_in[1];
  const float* in_w   = (const float*)d_in[2];
  const float* conv_w = (const float*)d_in[3];
  const float* conv_b = (const float*)d_in[4];
  const float* xp_w   = (const float*)d_in[5];
  const float* dt_w   = (const float*)d_in[6];
  const float* dt_b   = (const float*)d_in[7];
  const float* A_log  = (const float*)d_in[8];
  const float* Dp     = (const float*)d_in[9];
  const float* out_w  = (const float*)d_in[10];
  const float* normf  = (const float*)d_in[11];
  float* out = (float*)d_out;

  float* ws = (float*)d_ws;
  const size_t TD = (size_t)SEQ * D_MODEL;            // 2M
  const size_t TI = (size_t)SEQ * D_INNER;            // 4M
  const size_t ST = (size_t)NCH * D_INNER * NSTATE;   // 4.19M (CL=16)
  const size_t DB = (size_t)SEQ * DPROJ;              // 196608
  const size_t INW = (size_t)2 * D_INNER * D_MODEL;   // 4.19M
  const size_t XPW = (size_t)DPROJ * D_INNER;
  const size_t DTW = (size_t)D_INNER * DT_RANK;
  const size_t OUW = (size_t)D_MODEL * D_INNER;

  float* res   = ws; ws += TD;
  float* dbc   = ws; ws += DB;
  float* pk    = ws; ws += ST;   // kpart (x_proj 16*DB, out_proj 2*TD) & aprod alias
  float* hend  = ws; ws += ST;   // becomes hin after passB
  ushort_t* hnb  = (ushort_t*)ws;
  ushort_t* xzb  = hnb + TD;        // 2*TI ushorts
  ushort_t* xcb  = xzb + 2 * TI;
  ushort_t* dtbb = xcb + TI;
  ushort_t* ybf  = dtbb + TI;
  ushort_t* dbcb = ybf + TI;
  ushort_t* inwb = dbcb + DB;           // 2*INW (both layers)
  ushort_t* xpwb = inwb + 2 * INW;      // 2*XPW
  ushort_t* dtwb = xpwb + 2 * XPW;      // 2*DTW
  ushort_t* ouwb = dtwb + 2 * DTW;      // 2*OUW

  // convert ALL weights (both layers) in one dispatch
  {
    int n0 = (int)(2 * INW / 4), n1 = (int)(2 * XPW / 4);
    int n2 = (int)(2 * DTW / 4), n3 = (int)(2 * OUW / 4);
    int tot = n0 + n1 + n2 + n3;
    f2bf_all_kernel<<<(tot + 255) / 256, 256, 0, stream>>>(
        in_w, inwb, n0, xp_w, xpwb, n1, dt_w, dtwb, n2, out_w, ouwb, n3);
  }

  for (int i = 0; i < 2; ++i) {
    // residual update + rmsnorm; layer>0 consumes out_proj split-K partials
    addrms_kernel<<<SEQ, 256, 0, stream>>>(
        i == 0 ? h_in : pk, i == 0 ? nullptr : pk + TD,
        i == 0 ? nullptr : res,
        norm_w + (size_t)i * D_MODEL, res, nullptr, hnb);
    // in_proj: [2048 x 1024] x [4096 x 1024]^T -> xzb (bf16) [2048 x 4096]
    gemm_bt<1, false, 2><<<dim3(32, 16, 1), 256, 0, stream>>>(
        hnb, inwb + (size_t)i * INW, xzb, nullptr,
        SEQ, 2 * D_INNER, D_MODEL, D_MODEL, D_MODEL, 2 * D_INNER);
    conv_silu_kernel<<<(int)(TI / 4 / 256), 256, 0, stream>>>(
        xzb, conv_w + (size_t)i * D_INNER * 4, conv_b + (size_t)i * D_INNER, xcb);
    // x_proj: [2048 x 2048] x [96 x 2048]^T, split-K=16 -> pk (f32)
    gemm_bt<16, true, 0><<<dim3(1, 16, 16), 256, 0, stream>>>(
        xcb, xpwb + (size_t)i * XPW, pk, nullptr,
        SEQ, DPROJ, D_INNER, D_INNER, D_INNER, DPROJ);
    reduceN_kernel<<<(DB + 255) / 256, 256, 0, stream>>>(pk, dbc, dbcb, (int)DB, 16);
    // dt_proj: [2048 x 96(use 64)] x [2048 x 64]^T -> softplus(.+b) -> dtbb (bf16)
    gemm_bt<1, false, 1><<<dim3(16, 16, 1), 256, 0, stream>>>(
        dbcb, dtwb + (size_t)i * DTW, dtbb, dt_b + (size_t)i * D_INNER,
        SEQ, D_INNER, DT_RANK, DPROJ, DT_RANK, D_INNER);
    scan_passA_kernel<<<dim3(NCH, D_INNER / 256), 256, 0, stream>>>(
        dtbb, xcb, dbc, A_log + (size_t)i * D_INNER * NSTATE, pk, hend);
    scan_passB_kernel<<<(D_INNER * NSTATE) / 64, 256, 0, stream>>>(pk, hend);
    scan_passC_kernel<<<dim3(NCH, D_INNER / 256), 256, 0, stream>>>(
        dtbb, xcb, dbc, A_log + (size_t)i * D_INNER * NSTATE,
        Dp + (size_t)i * D_INNER, xzb, hend, ybf);
    // out_proj: [2048 x 2048] x [1024 x 2048]^T, split-K=2 -> pk partials
    gemm_bt<2, false, 0><<<dim3(8, 16, 2), 256, 0, stream>>>(
        ybf, ouwb + (size_t)i * OUW, pk, nullptr,
        SEQ, D_MODEL, D_INNER, D_INNER, D_INNER, D_MODEL);
  }
  // final: rmsnorm(out_proj partials + res) -> out (f32)
  addrms_kernel<<<SEQ, 256, 0, stream>>>(pk, pk + TD, res, normf,
                                         nullptr, out, nullptr);
}

// Round 9
// 388.828 us; speedup vs baseline: 1.1209x; 1.0023x over previous
//
#include <hip/hip_runtime.h>
#include <math.h>

#define D_MODEL 1024
#define D_INNER 2048
#define DPROJ   96      // DT_RANK + 2*D_STATE
#define DT_RANK 64
#define NSTATE  16
#define SEQ     2048
#define CL      16      // chunk length for scan
#define NCH     (SEQ/CL)            // 128
#define SCAN_SEGS 4
#define SCAN_CPS  (NCH / SCAN_SEGS) // 32 chunks per segment-lane
#define LOG2E   1.44269504088896340736f

typedef unsigned short ushort_t;
typedef short v8s __attribute__((ext_vector_type(8)));
typedef float v4f __attribute__((ext_vector_type(4)));
typedef __attribute__((address_space(3))) unsigned int as3_u32;
typedef __attribute__((address_space(1))) unsigned int as1_u32;

__device__ __forceinline__ float silu_f(float x) { return x / (1.f + expf(-x)); }

__device__ __forceinline__ ushort_t f2bf(float f) {
  union { float f; unsigned u; } x; x.f = f;
  unsigned r = x.u + 0x7fffu + ((x.u >> 16) & 1u);  // RNE; inputs finite
  return (ushort_t)(r >> 16);
}
__device__ __forceinline__ float bf2f(ushort_t b) {
  union { unsigned u; float f; } x; x.u = ((unsigned)b) << 16; return x.f;
}

// async global->LDS, 16B per lane; lds dest = wave-uniform base + lane*16
__device__ __forceinline__ void gl_lds16(const ushort_t* g, ushort_t* l) {
  __builtin_amdgcn_global_load_lds((const as1_u32*)g, (as3_u32*)l, 16, 0, 0);
}

// res = a (+a2+a3+a4) (+ b); xn = rmsnorm(res)*w -> f32 (xnf) and/or bf16 (xnb)
// a2..a4 consume split-K=4 GEMM partials directly (fixed order, deterministic)
__global__ __launch_bounds__(256) void addrms_kernel(
    const float* __restrict__ a, const float* __restrict__ a2,
    const float* __restrict__ a3, const float* __restrict__ a4,
    const float* __restrict__ b,
    const float* __restrict__ w, float* __restrict__ res_out,
    float* __restrict__ xnf, ushort_t* __restrict__ xnb) {
  int t = blockIdx.x;
  int tid = threadIdx.x;
  float v[4];
  float ss = 0.f;
#pragma unroll
  for (int j = 0; j < 4; ++j) {
    int dcol = tid + j * 256;
    size_t off = (size_t)t * D_MODEL + dcol;
    float x = a[off];
    if (a2) x += a2[off];
    if (a3) x += a3[off];
    if (a4) x += a4[off];
    if (b) x += b[off];
    v[j] = x;
    ss += x * x;
  }
#pragma unroll
  for (int off = 32; off > 0; off >>= 1) ss += __shfl_down(ss, off);
  __shared__ float red[4];
  __shared__ float rmsv;
  int wid = tid >> 6, lane = tid & 63;
  if (lane == 0) red[wid] = ss;
  __syncthreads();
  if (tid == 0) {
    float s = red[0] + red[1] + red[2] + red[3];
    rmsv = rsqrtf(s / (float)D_MODEL + 1e-5f);
  }
  __syncthreads();
  float r = rmsv;
#pragma unroll
  for (int j = 0; j < 4; ++j) {
    int dcol = tid + j * 256;
    if (res_out) res_out[(size_t)t * D_MODEL + dcol] = v[j];
    float xn = v[j] * r * w[dcol];
    if (xnf) xnf[(size_t)t * D_MODEL + dcol] = xn;
    if (xnb) xnb[(size_t)t * D_MODEL + dcol] = f2bf(xn);
  }
}

// single-dispatch f32->bf16 of all 4 weight tensors (both layers each)
__global__ __launch_bounds__(256) void f2bf_all_kernel(
    const float* __restrict__ s0, ushort_t* __restrict__ d0, int n0,
    const float* __restrict__ s1, ushort_t* __restrict__ d1, int n1,
    const float* __restrict__ s2, ushort_t* __restrict__ d2, int n2,
    const float* __restrict__ s3, ushort_t* __restrict__ d3, int n3) {
  int j = blockIdx.x * 256 + threadIdx.x;
  const float* s; ushort_t* d;
  if (j < n0) { s = s0; d = d0; }
  else {
    j -= n0;
    if (j < n1) { s = s1; d = d1; }
    else {
      j -= n1;
      if (j < n2) { s = s2; d = d2; }
      else {
        j -= n2;
        if (j >= n3) return;
        s = s3; d = d3;
      }
    }
  }
  float4 v = ((const float4*)s)[j];
  ushort4 o;
  o.x = f2bf(v.x); o.y = f2bf(v.y); o.z = f2bf(v.z); o.w = f2bf(v.w);
  ((ushort4*)d)[j] = o;
}

// ------------- bf16 MFMA GEMM (NT): C[m,n] = sum_k A[m,k]*B[n,k] -------------
// m97 structure + double-buffered prefetch; one __syncthreads per K-step.
// EPI: 0 = f32 out, 1 = softplus(acc+bias[col]) -> bf16, 2 = bf16,
//      3 = pack( bf16(softplus(acc+bias)) | upack[idx]<<16 ) -> uint out.
template <int SPLITK, bool CLAMPN, int EPI>
__global__ __launch_bounds__(256) void gemm_bt(
    const ushort_t* __restrict__ A, const ushort_t* __restrict__ B,
    void* __restrict__ Cv, const float* __restrict__ bias,
    const ushort_t* __restrict__ upack,
    int M, int N, int K, int lda, int ldb, int ldc) {
  __shared__ ushort_t As[2][128 * 32];
  __shared__ ushort_t Bs[2][128 * 32];
  int tid = threadIdx.x;
  int bm = blockIdx.y * 128;
  int bn = blockIdx.x * 128;
  int kchunk = K / SPLITK;
  int k0 = blockIdx.z * kchunk;
  int nk = kchunk / 32;

  int lane = tid & 63, wid = tid >> 6;
  int wr = wid >> 1, wc = wid & 1;
  int lr = lane & 15;
  int ko = (lane >> 4) * 8;

  int rs0 = wid * 16 + (lane >> 2);
  int segc = (lane & 3) * 8;

  auto stage = [&](int buf, int kt) {
#pragma unroll
    for (int s = 0; s < 2; ++s) {
      int r = s * 64 + rs0;
      int cc = kt + segc;
      gl_lds16(A + (size_t)(bm + r) * lda + cc, &As[buf][s * 2048 + wid * 512]);
      int bc = bn + r;
      if (CLAMPN) bc = min(bc, N - 1);   // in-bounds; junk cols never stored
      gl_lds16(B + (size_t)bc * ldb + cc, &Bs[buf][s * 2048 + wid * 512]);
    }
  };

  v4f acc[4][4] = {};

  stage(0, k0);
  __syncthreads();
  int cur = 0;
  for (int it = 0; it < nk; ++it) {
    if (it + 1 < nk) stage(cur ^ 1, k0 + (it + 1) * 32);
    v8s a[4], b[4];
#pragma unroll
    for (int m = 0; m < 4; ++m)
      a[m] = *(const v8s*)&As[cur][(wr * 64 + m * 16 + lr) * 32 + ko];
#pragma unroll
    for (int n = 0; n < 4; ++n)
      b[n] = *(const v8s*)&Bs[cur][(wc * 64 + n * 16 + lr) * 32 + ko];
#pragma unroll
    for (int m = 0; m < 4; ++m)
#pragma unroll
      for (int n = 0; n < 4; ++n)
        acc[m][n] = __builtin_amdgcn_mfma_f32_16x16x32_bf16(a[m], b[n], acc[m][n], 0, 0, 0);
    __syncthreads();
    cur ^= 1;
  }

  float* Cf = (float*)Cv;
  ushort_t* Cb = (ushort_t*)Cv;
  unsigned* Cu = (unsigned*)Cv;
  if (SPLITK > 1) Cf += (size_t)blockIdx.z * (size_t)M * (size_t)ldc;

#pragma unroll
  for (int m = 0; m < 4; ++m) {
#pragma unroll
    for (int n = 0; n < 4; ++n) {
      int gc = bn + wc * 64 + n * 16 + lr;
      if (gc >= N) continue;
      int gr0 = bm + wr * 64 + m * 16 + (lane >> 4) * 4;
      float bv = (EPI == 1 || EPI == 3) ? bias[gc] : 0.f;
#pragma unroll
      for (int j = 0; j < 4; ++j) {
        float val = acc[m][n][j];
        size_t idx = (size_t)(gr0 + j) * ldc + gc;
        if (EPI == 0) {
          Cf[idx] = val;
        } else if (EPI == 1) {
          float x = val + bv;
          x = fmaxf(x, 0.f) + log1pf(expf(-fabsf(x)));
          Cb[idx] = f2bf(x);
        } else if (EPI == 2) {
          Cb[idx] = f2bf(val);
        } else {
          float x = val + bv;
          x = fmaxf(x, 0.f) + log1pf(expf(-fabsf(x)));
          Cu[idx] = (unsigned)f2bf(x) | ((unsigned)upack[idx] << 16);
        }
      }
    }
  }
}

// out[idx] = sum_p part[idx + p*sz]; optional bf16 mirror
__global__ __launch_bounds__(256) void reduceN_kernel(
    const float* __restrict__ part, float* __restrict__ out,
    ushort_t* __restrict__ outb, int sz, int nparts) {
  int idx = blockIdx.x * 256 + threadIdx.x;
  if (idx >= sz) return;
  float s = 0.f;
  for (int p = 0; p < nparts; ++p) s += part[idx + (size_t)p * sz];
  out[idx] = s;
  if (outb) outb[idx] = f2bf(s);
}

// depthwise causal conv (k=4) + silu, bf16 in (xz) -> bf16 out; 4 channels/thread
__global__ __launch_bounds__(256) void conv_silu_kernel(
    const ushort_t* __restrict__ xzb, const float* __restrict__ cw,
    const float* __restrict__ cb, ushort_t* __restrict__ xcb) {
  int idx = blockIdx.x * 256 + threadIdx.x;   // over SEQ * (D_INNER/4)
  int t = idx >> 9;
  int c = (idx & 511) * 4;
  float acc[4];
  float4 cbv = *(const float4*)&cb[c];
  acc[0] = cbv.x; acc[1] = cbv.y; acc[2] = cbv.z; acc[3] = cbv.w;
  float4 wv[4];
#pragma unroll
  for (int i = 0; i < 4; ++i) wv[i] = *(const float4*)&cw[(c + i) * 4];
#pragma unroll
  for (int k = 0; k < 4; ++k) {
    int ts = t - 3 + k;
    if (ts < 0) continue;
    ushort4 x = *(const ushort4*)&xzb[(size_t)ts * 4096 + c];
    acc[0] = fmaf(bf2f(x.x), ((const float*)&wv[0])[k], acc[0]);
    acc[1] = fmaf(bf2f(x.y), ((const float*)&wv[1])[k], acc[1]);
    acc[2] = fmaf(bf2f(x.z), ((const float*)&wv[2])[k], acc[2]);
    acc[3] = fmaf(bf2f(x.w), ((const float*)&wv[3])[k], acc[3]);
  }
  ushort4 o;
  o.x = f2bf(silu_f(acc[0]));
  o.y = f2bf(silu_f(acc[1]));
  o.z = f2bf(silu_f(acc[2]));
  o.w = f2bf(silu_f(acc[3]));
  *(ushort4*)&xcb[(size_t)t * D_INNER + c] = o;
}

// Pass A: per-chunk cumulative dA product + local end state (h0 = 0).
// dt/u packed in dtu (1 dword per t); B rows staged in LDS.
__global__ __launch_bounds__(256) void scan_passA_kernel(
    const unsigned* __restrict__ dtu, const float* __restrict__ dbc,
    const float* __restrict__ A_log,
    float* __restrict__ aprod, float* __restrict__ hend) {
  __shared__ float Bsh[CL][16];
  int c = blockIdx.x;
  int d = blockIdx.y * 256 + threadIdx.x;
  int t0 = c * CL;
  {
    int j = threadIdx.x;           // CL*16/4 = 64 float4 slots
    if (j < CL * 4) {
      int r = j >> 2, col = (j & 3) * 4;
      *(float4*)&Bsh[r][col] = *(const float4*)&dbc[(size_t)(t0 + r) * DPROJ + DT_RANK + col];
    }
  }
  float Av[NSTATE], h[NSTATE], ap[NSTATE];
#pragma unroll
  for (int n = 0; n < NSTATE; ++n) {
    Av[n] = -expf(A_log[(size_t)d * NSTATE + n]) * LOG2E;
    h[n] = 0.f;
    ap[n] = 1.f;
  }
  __syncthreads();
#pragma unroll 2
  for (int tt = 0; tt < CL; ++tt) {
    unsigned p = dtu[(size_t)(t0 + tt) * D_INNER + d];
    float dtv = bf2f((ushort_t)(p & 0xffffu));
    float uv  = bf2f((ushort_t)(p >> 16));
    float du = dtv * uv;
#pragma unroll
    for (int n = 0; n < NSTATE; ++n) {
      float dA = exp2f(dtv * Av[n]);
      h[n] = fmaf(dA, h[n], du * Bsh[tt][n]);
      ap[n] *= dA;
    }
  }
  size_t base = ((size_t)c * D_INNER + d) * NSTATE;
#pragma unroll
  for (int n = 0; n < NSTATE; ++n) {
    aprod[base + n] = ap[n];
    hend[base + n] = h[n];
  }
}

// Pass B: carry across 128 chunks. Each chain (d,n) owned by 4 lanes x 32 chunks,
// (a,e) in registers; shfl composes segment (P,E); in-register rescan rewrites
// hend with the INCOMING state per chunk.
__global__ __launch_bounds__(256) void scan_passB_kernel(
    const float* __restrict__ aprod, float* __restrict__ hend_hin) {
  int tid = threadIdx.x;
  int lane = tid & 63;
  int wave = tid >> 6;
  int seg = lane >> 4;                       // 0..3
  int chain = blockIdx.x * 64 + wave * 16 + (lane & 15);
  const size_t stride = (size_t)D_INNER * NSTATE;
  float a[SCAN_CPS], e[SCAN_CPS];
  float P = 1.f, E = 0.f;
  int c0 = seg * SCAN_CPS;
#pragma unroll
  for (int j = 0; j < SCAN_CPS; ++j) {
    a[j] = aprod[(size_t)(c0 + j) * stride + chain];
    e[j] = hend_hin[(size_t)(c0 + j) * stride + chain];
    E = fmaf(a[j], E, e[j]);
    P *= a[j];
  }
#pragma unroll
  for (int dstep = 1; dstep < SCAN_SEGS; dstep <<= 1) {
    float Pp = __shfl_up(P, dstep * 16);
    float Ep = __shfl_up(E, dstep * 16);
    if (seg >= dstep) { E = fmaf(P, Ep, E); P *= Pp; }
  }
  float Ex = __shfl_up(E, 16);
  if (seg == 0) Ex = 0.f;
  float h = Ex;
#pragma unroll
  for (int j = 0; j < SCAN_CPS; ++j) {
    hend_hin[(size_t)(c0 + j) * stride + chain] = h;
    h = fmaf(a[j], h, e[j]);
  }
}

// Pass C: rescan from hin; y = (scan + u*D) * silu(z) -> bf16.
// dt/u packed; B and C rows staged in LDS.
__global__ __launch_bounds__(256) void scan_passC_kernel(
    const unsigned* __restrict__ dtu, const float* __restrict__ dbc,
    const float* __restrict__ A_log, const float* __restrict__ Dp,
    const ushort_t* __restrict__ xzb, const float* __restrict__ hin,
    ushort_t* __restrict__ yb) {
  __shared__ float BCsh[CL][32];   // [tt][0..15]=B, [16..31]=C
  int c = blockIdx.x;
  int d = blockIdx.y * 256 + threadIdx.x;
  int t0 = c * CL;
  {
    int j = threadIdx.x;           // CL*32/4 = 128 float4 slots
    if (j < CL * 8) {
      int r = j >> 3, col = (j & 7) * 4;
      *(float4*)&BCsh[r][col] = *(const float4*)&dbc[(size_t)(t0 + r) * DPROJ + DT_RANK + col];
    }
  }
  float Av[NSTATE], h[NSTATE];
  size_t base = ((size_t)c * D_INNER + d) * NSTATE;
#pragma unroll
  for (int n = 0; n < NSTATE; ++n) {
    Av[n] = -expf(A_log[(size_t)d * NSTATE + n]) * LOG2E;
    h[n] = hin[base + n];
  }
  float Dv = Dp[d];
  __syncthreads();
#pragma unroll 2
  for (int tt = 0; tt < CL; ++tt) {
    unsigned p = dtu[(size_t)(t0 + tt) * D_INNER + d];
    float dtv = bf2f((ushort_t)(p & 0xffffu));
    float uv  = bf2f((ushort_t)(p >> 16));
    float du = dtv * uv;
    float yv = 0.f;
#pragma unroll
    for (int n = 0; n < NSTATE; ++n) {
      float dA = exp2f(dtv * Av[n]);
      h[n] = fmaf(dA, h[n], du * BCsh[tt][n]);
      yv = fmaf(h[n], BCsh[tt][16 + n], yv);
    }
    float zv = bf2f(xzb[(size_t)(t0 + tt) * 4096 + D_INNER + d]);
    yb[(size_t)(t0 + tt) * D_INNER + d] = f2bf((yv + uv * Dv) * silu_f(zv));
  }
}

extern "C" void kernel_launch(void* const* d_in, const int* in_sizes, int n_in,
                              void* d_out, int out_size, void* d_ws, size_t ws_size,
                              hipStream_t stream) {
  const float* h_in   = (const float*)d_in[0];
  const float* norm_w = (const float*)d_in[1];
  const float* in_w   = (const float*)d_in[2];
  const float* conv_w = (const float*)d_in[3];
  const float* conv_b = (const float*)d_in[4];
  const float* xp_w   = (const float*)d_in[5];
  const float* dt_w   = (const float*)d_in[6];
  const float* dt_b   = (const float*)d_in[7];
  const float* A_log  = (const float*)d_in[8];
  const float* Dp     = (const float*)d_in[9];
  const float* out_w  = (const float*)d_in[10];
  const float* normf  = (const float*)d_in[11];
  float* out = (float*)d_out;

  float* ws = (float*)d_ws;
  const size_t TD = (size_t)SEQ * D_MODEL;            // 2.10M
  const size_t TI = (size_t)SEQ * D_INNER;            // 4.19M
  const size_t ST = (size_t)NCH * D_INNER * NSTATE;   // 4.19M == 2*TD
  const size_t DB = (size_t)SEQ * DPROJ;
  const size_t INW = (size_t)2 * D_INNER * D_MODEL;
  const size_t XPW = (size_t)DPROJ * D_INNER;
  const size_t DTW = (size_t)D_INNER * DT_RANK;
  const size_t OUW = (size_t)D_MODEL * D_INNER;

  float* res   = ws; ws += TD;
  float* dbc   = ws; ws += DB;
  float* pk    = ws; ws += ST;   // x_proj partials / aprod / out_proj partials 0-1
  float* hend  = ws; ws += ST;   // hin after passB / out_proj partials 2-3 (pk+2TD)
  unsigned* dtu = (unsigned*)ws; ws += TI;
  ushort_t* hnb  = (ushort_t*)ws;
  ushort_t* xzb  = hnb + TD;        // 2*TI ushorts
  ushort_t* xcb  = xzb + 2 * TI;
  ushort_t* ybf  = xcb + TI;
  ushort_t* dbcb = ybf + TI;
  ushort_t* inwb = dbcb + DB;           // 2*INW (both layers)
  ushort_t* xpwb = inwb + 2 * INW;
  ushort_t* dtwb = xpwb + 2 * XPW;
  ushort_t* ouwb = dtwb + 2 * DTW;

  // convert ALL weights (both layers) in one dispatch
  {
    int n0 = (int)(2 * INW / 4), n1 = (int)(2 * XPW / 4);
    int n2 = (int)(2 * DTW / 4), n3 = (int)(2 * OUW / 4);
    int tot = n0 + n1 + n2 + n3;
    f2bf_all_kernel<<<(tot + 255) / 256, 256, 0, stream>>>(
        in_w, inwb, n0, xp_w, xpwb, n1, dt_w, dtwb, n2, out_w, ouwb, n3);
  }

  for (int i = 0; i < 2; ++i) {
    // residual update + rmsnorm; layer>0 consumes out_proj split-K=4 partials
    addrms_kernel<<<SEQ, 256, 0, stream>>>(
        i == 0 ? h_in : pk,
        i == 0 ? nullptr : pk + TD,
        i == 0 ? nullptr : pk + 2 * TD,
        i == 0 ? nullptr : pk + 3 * TD,
        i == 0 ? nullptr : res,
        norm_w + (size_t)i * D_MODEL, res, nullptr, hnb);
    // in_proj: [2048 x 1024] x [4096 x 1024]^T -> xzb (bf16)
    gemm_bt<1, false, 2><<<dim3(32, 16, 1), 256, 0, stream>>>(
        hnb, inwb + (size_t)i * INW, xzb, nullptr, nullptr,
        SEQ, 2 * D_INNER, D_MODEL, D_MODEL, D_MODEL, 2 * D_INNER);
    conv_silu_kernel<<<(int)(TI / 4 / 256), 256, 0, stream>>>(
        xzb, conv_w + (size_t)i * D_INNER * 4, conv_b + (size_t)i * D_INNER, xcb);
    // x_proj: split-K=16 -> pk, reduce -> dbc (f32) + dbcb (bf16)
    gemm_bt<16, true, 0><<<dim3(1, 16, 16), 256, 0, stream>>>(
        xcb, xpwb + (size_t)i * XPW, pk, nullptr, nullptr,
        SEQ, DPROJ, D_INNER, D_INNER, D_INNER, DPROJ);
    reduceN_kernel<<<(DB + 255) / 256, 256, 0, stream>>>(pk, dbc, dbcb, (int)DB, 16);
    // dt_proj -> softplus -> packed (dt | u<<16) uint buffer
    gemm_bt<1, false, 3><<<dim3(16, 16, 1), 256, 0, stream>>>(
        dbcb, dtwb + (size_t)i * DTW, dtu, dt_b + (size_t)i * D_INNER, xcb,
        SEQ, D_INNER, DT_RANK, DPROJ, DT_RANK, D_INNER);
    // scan: A -> B -> C (3 dispatches, verified structure)
    scan_passA_kernel<<<dim3(NCH, D_INNER / 256), 256, 0, stream>>>(
        dtu, dbc, A_log + (size_t)i * D_INNER * NSTATE, pk, hend);
    scan_passB_kernel<<<(D_INNER * NSTATE) / 64, 256, 0, stream>>>(pk, hend);
    scan_passC_kernel<<<dim3(NCH, D_INNER / 256), 256, 0, stream>>>(
        dtu, dbc, A_log + (size_t)i * D_INNER * NSTATE,
        Dp + (size_t)i * D_INNER, xzb, hend, ybf);
    // out_proj: split-K=4 -> pk..pk+4*TD (pk and hend are contiguous, ST==2*TD)
    gemm_bt<4, false, 0><<<dim3(8, 16, 4), 256, 0, stream>>>(
        ybf, ouwb + (size_t)i * OUW, pk, nullptr, nullptr,
        SEQ, D_MODEL, D_INNER, D_INNER, D_INNER, D_MODEL);
  }
  addrms_kernel<<<SEQ, 256, 0, stream>>>(
      pk, pk + TD, pk + 2 * TD, pk + 3 * TD, res, normf, nullptr, out, nullptr);
}